// Round 1
// 632.373 us; speedup vs baseline: 1.0970x; 1.0970x over previous
//
#include <hip/hip_runtime.h>

#define F_TOTAL 128
#define N_HEADS 8
#define HEAD_DIM 16
#define SCAN_ITEMS 1024   // items per block in the node-histogram scan

typedef float vf4 __attribute__((ext_vector_type(4)));
typedef int   vi4 __attribute__((ext_vector_type(4)));
typedef float vf2 __attribute__((ext_vector_type(2)));

// ---------------------------------------------------------------------------
// Kernel 1: per-head linear projections q,k,v = x_h @ W_h^T  (fp32 in/out).
// Shuffle-based: no LDS, no barriers. Each thread owns one output feature f
// (f = tid&127 stays constant across grid-stride because stride % 128 == 0)
// and keeps the 3x16 weight rows in registers. k,v are stored INTERLEAVED
// as float2 {k,v} so the hot kernel gathers them with contiguous dwordx4.
// The pair histogram (independent work) is fused in to save a dispatch.
// ---------------------------------------------------------------------------
__global__ __launch_bounds__(256) void proj_hist_kernel(
    const float* __restrict__ x,
    const float* __restrict__ wq,
    const float* __restrict__ wk,
    const float* __restrict__ wv,
    const int*   __restrict__ idx_i,
    float* __restrict__ q, float* __restrict__ kv,
    int*   __restrict__ hist,
    int n_nodes, int n_pairs)
{
    const int gid = blockIdx.x * 256 + threadIdx.x;
    const int stride = gridDim.x * 256;
    const int f = gid & (F_TOTAL - 1);

    float rq[16], rk[16], rv[16];
    const float4* wq4 = (const float4*)wq;
    const float4* wk4 = (const float4*)wk;
    const float4* wv4 = (const float4*)wv;
    #pragma unroll
    for (int d4 = 0; d4 < 4; ++d4) {
        float4 a = wq4[f * 4 + d4];
        rq[d4*4+0]=a.x; rq[d4*4+1]=a.y; rq[d4*4+2]=a.z; rq[d4*4+3]=a.w;
        float4 b = wk4[f * 4 + d4];
        rk[d4*4+0]=b.x; rk[d4*4+1]=b.y; rk[d4*4+2]=b.z; rk[d4*4+3]=b.w;
        float4 c = wv4[f * 4 + d4];
        rv[d4*4+0]=c.x; rv[d4*4+1]=c.y; rv[d4*4+2]=c.z; rv[d4*4+3]=c.w;
    }
    // lane holding x[n][h*16+d] within this thread's wave
    const int lanebase = (f & 112) & 63;

    const int total = n_nodes * F_TOTAL;
    for (int idx = gid; idx < total; idx += stride) {
        const float xval = __builtin_nontemporal_load(x + idx);  // read-once
        float aq = 0.f, ak = 0.f, av = 0.f;
        #pragma unroll
        for (int d = 0; d < 16; ++d) {
            const float xv = __shfl(xval, lanebase + d);
            aq += xv * rq[d];
            ak += xv * rk[d];
            av += xv * rv[d];
        }
        q[idx] = aq;
        ((vf2*)kv)[idx] = (vf2){ak, av};
    }

    // fused pair histogram (grid covers 786k threads > 640k pairs)
    for (int p = gid; p < n_pairs; p += stride)
        atomicAdd(&hist[idx_i[p]], 1);
}

// ---------------------------------------------------------------------------
// Counting sort of pairs by idx_i: hist -> scan -> scatter. Payload packed
// into one int4 {p, j, phi_bits, 0}: one scattered 16B store per pair, one
// broadcast 16B load per pair in the hot kernel.
// ---------------------------------------------------------------------------
__global__ __launch_bounds__(256) void scan_reduce_kernel(
    const int* __restrict__ hist, int* __restrict__ blockSums, int n)
{
    __shared__ int ls[256];
    const int t = threadIdx.x;
    const int base = blockIdx.x * SCAN_ITEMS + t * 4;
    int s = 0;
    if (base + 3 < n) {
        int4 h = *(const int4*)(hist + base);
        s = h.x + h.y + h.z + h.w;
    } else {
        for (int kk = 0; kk < 4; ++kk)
            if (base + kk < n) s += hist[base + kk];
    }
    ls[t] = s;
    __syncthreads();
    for (int off = 128; off > 0; off >>= 1) {
        if (t < off) ls[t] += ls[t + off];
        __syncthreads();
    }
    if (t == 0) blockSums[blockIdx.x] = ls[0];
}

__global__ __launch_bounds__(128) void scan_spine_kernel(
    int* __restrict__ blockSums, int nblk)
{
    __shared__ int ls[128];
    const int t = threadIdx.x;
    const int val = (t < nblk) ? blockSums[t] : 0;
    ls[t] = val;
    __syncthreads();
    for (int off = 1; off < 128; off <<= 1) {
        int add = (t >= off) ? ls[t - off] : 0;
        __syncthreads();
        ls[t] += add;
        __syncthreads();
    }
    if (t < nblk) blockSums[t] = ls[t] - val;   // exclusive
}

__global__ __launch_bounds__(256) void scan_apply_kernel(
    const int* __restrict__ hist, const int* __restrict__ blockSums,
    int* __restrict__ offsets, int n)
{
    __shared__ int ls[256];
    const int t = threadIdx.x;
    const int base = blockIdx.x * SCAN_ITEMS + t * 4;
    int h0 = 0, h1 = 0, h2 = 0, h3 = 0;
    if (base + 3 < n) {
        int4 h = *(const int4*)(hist + base);
        h0 = h.x; h1 = h.y; h2 = h.z; h3 = h.w;
    } else {
        if (base + 0 < n) h0 = hist[base + 0];
        if (base + 1 < n) h1 = hist[base + 1];
        if (base + 2 < n) h2 = hist[base + 2];
        if (base + 3 < n) h3 = hist[base + 3];
    }
    const int tsum = h0 + h1 + h2 + h3;
    ls[t] = tsum;
    __syncthreads();
    for (int off = 1; off < 256; off <<= 1) {
        int add = (t >= off) ? ls[t - off] : 0;
        __syncthreads();
        ls[t] += add;
        __syncthreads();
    }
    int off = blockSums[blockIdx.x] + (ls[t] - tsum);   // exclusive base
    if (base + 0 < n) offsets[base + 0] = off; off += h0;
    if (base + 1 < n) offsets[base + 1] = off; off += h1;
    if (base + 2 < n) offsets[base + 2] = off; off += h2;
    if (base + 3 < n) offsets[base + 3] = off;
}

// scatter bumps offsets[] directly (no cursor array): afterwards
// offsets[i] == start_i + cnt_i, and the hot kernel recovers
// start_i = offsets[i] - hist[i].
__global__ __launch_bounds__(256) void scatter_kernel(
    const int* __restrict__ idx_i, const int* __restrict__ idx_j,
    const float* __restrict__ phi,
    int* __restrict__ offsets,
    vi4* __restrict__ meta,
    int n_pairs)
{
    const int p = blockIdx.x * 256 + threadIdx.x;
    if (p < n_pairs) {
        const int i = idx_i[p];
        const int pos = atomicAdd(&offsets[i], 1);
        meta[pos] = (vi4){p, idx_j[p], __float_as_int(phi[p]), 0};
    }
}

// ---------------------------------------------------------------------------
// Kernel 3: segmented attention aggregation, float4 per thread.
// 32 threads per node (8 nodes per 256-thread block); thread t owns features
// f = 4t..4t+3 (always within one head since 4 | 16). Per pair: one int4
// meta load (wave-broadcast), one dwordx4 w load (nontemporal: stream-once),
// two dwordx4 interleaved {k,v} loads, 2 shfl_xor for the 16-wide head
// reduce. ~4x fewer VMEM and ~8x fewer DS instructions than the scalar
// version at identical byte traffic. No atomics, one dwordx4 store.
// ---------------------------------------------------------------------------
__global__ __launch_bounds__(256) void segment_kernel(
    const float* __restrict__ q,
    const float* __restrict__ kv,
    const float* __restrict__ w_ij,
    const int* __restrict__ hist,
    const int* __restrict__ offsets,
    const vi4* __restrict__ meta,
    float* __restrict__ out,
    int n_nodes)
{
    const int node = blockIdx.x * 8 + (threadIdx.x >> 5);
    const int t = threadIdx.x & 31;
    if (node >= n_nodes) return;

    const int cnt = hist[node];
    const int start = offsets[node] - cnt;   // offsets were advanced by scatter

    const vf4 q4 = *((const vf4*)(q + (size_t)node * F_TOTAL) + t);
    vf4 acc = (vf4){0.f, 0.f, 0.f, 0.f};

    int c = 0;
    for (; c + 2 <= cnt; c += 2) {
        const vi4 m0 = meta[start + c];
        const vi4 m1 = meta[start + c + 1];
        const vf4 w0 = __builtin_nontemporal_load(
            (const vf4*)(w_ij + (size_t)m0.x * F_TOTAL) + t);
        const vf4 w1 = __builtin_nontemporal_load(
            (const vf4*)(w_ij + (size_t)m1.x * F_TOTAL) + t);
        const vf4* kp0 = (const vf4*)(kv + (size_t)m0.y * F_TOTAL * 2) + t * 2;
        const vf4* kp1 = (const vf4*)(kv + (size_t)m1.y * F_TOTAL * 2) + t * 2;
        const vf4 a0 = kp0[0], b0 = kp0[1];   // {k0,v0,k1,v1} {k2,v2,k3,v3}
        const vf4 a1 = kp1[0], b1 = kp1[1];

        float t0 = q4.x*w0.x*a0.x + q4.y*w0.y*a0.z + q4.z*w0.z*b0.x + q4.w*w0.w*b0.z;
        float t1 = q4.x*w1.x*a1.x + q4.y*w1.y*a1.z + q4.z*w1.z*b1.x + q4.w*w1.w*b1.z;
        t0 += __shfl_xor(t0, 1); t0 += __shfl_xor(t0, 2);   // 16-wide head sum
        t1 += __shfl_xor(t1, 1); t1 += __shfl_xor(t1, 2);
        const float al0 = t0 * 0.25f * __int_as_float(m0.z);
        const float al1 = t1 * 0.25f * __int_as_float(m1.z);
        acc.x += al0 * a0.y; acc.y += al0 * a0.w;
        acc.z += al0 * b0.y; acc.w += al0 * b0.w;
        acc.x += al1 * a1.y; acc.y += al1 * a1.w;
        acc.z += al1 * b1.y; acc.w += al1 * b1.w;
    }
    for (; c < cnt; ++c) {
        const vi4 m0 = meta[start + c];
        const vf4 w0 = __builtin_nontemporal_load(
            (const vf4*)(w_ij + (size_t)m0.x * F_TOTAL) + t);
        const vf4* kp0 = (const vf4*)(kv + (size_t)m0.y * F_TOTAL * 2) + t * 2;
        const vf4 a0 = kp0[0], b0 = kp0[1];
        float t0 = q4.x*w0.x*a0.x + q4.y*w0.y*a0.z + q4.z*w0.z*b0.x + q4.w*w0.w*b0.z;
        t0 += __shfl_xor(t0, 1); t0 += __shfl_xor(t0, 2);
        const float al0 = t0 * 0.25f * __int_as_float(m0.z);
        acc.x += al0 * a0.y; acc.y += al0 * a0.w;
        acc.z += al0 * b0.y; acc.w += al0 * b0.w;
    }
    __builtin_nontemporal_store(acc, (vf4*)(out + (size_t)node * F_TOTAL) + t);
}

extern "C" void kernel_launch(void* const* d_in, const int* in_sizes, int n_in,
                              void* d_out, int out_size, void* d_ws, size_t ws_size,
                              hipStream_t stream)
{
    const float* x     = (const float*)d_in[0];
    const float* w_ij  = (const float*)d_in[1];
    const int*   idx_i = (const int*)d_in[2];
    const int*   idx_j = (const int*)d_in[3];
    const float* phi   = (const float*)d_in[4];
    const float* wq    = (const float*)d_in[5];
    const float* wk    = (const float*)d_in[6];
    const float* wv    = (const float*)d_in[7];

    const int n_nodes = in_sizes[0] / F_TOTAL;
    const int n_pairs = in_sizes[2];
    const size_t node_elems = (size_t)n_nodes * F_TOTAL;

    // workspace layout (16B-aligned segments first)
    float* q         = (float*)d_ws;                   // node_elems
    float* kv        = q + node_elems;                 // 2*node_elems (interleaved k,v)
    vi4*   meta      = (vi4*)(kv + 2 * node_elems);    // n_pairs
    int*   hist      = (int*)(meta + n_pairs);         // n_nodes
    int*   offsets   = hist + n_nodes;                 // n_nodes
    int*   blockSums = offsets + n_nodes;              // <=128 (pad to 128)

    hipMemsetAsync(hist, 0, (size_t)n_nodes * sizeof(int), stream);

    proj_hist_kernel<<<3072, 256, 0, stream>>>(
        x, wq, wk, wv, idx_i, q, kv, hist, n_nodes, n_pairs);

    const int nblk = (n_nodes + SCAN_ITEMS - 1) / SCAN_ITEMS;   // 98 for 100k
    scan_reduce_kernel<<<nblk, 256, 0, stream>>>(hist, blockSums, n_nodes);
    scan_spine_kernel<<<1, 128, 0, stream>>>(blockSums, nblk);
    scan_apply_kernel<<<nblk, 256, 0, stream>>>(hist, blockSums, offsets, n_nodes);

    const int pair_blocks = (n_pairs + 255) / 256;
    scatter_kernel<<<pair_blocks, 256, 0, stream>>>(
        idx_i, idx_j, phi, offsets, meta, n_pairs);

    segment_kernel<<<(n_nodes + 7) / 8, 256, 0, stream>>>(
        q, kv, w_ij, hist, offsets, meta, (float*)d_out, n_nodes);
}

// Round 2
// 631.426 us; speedup vs baseline: 1.0987x; 1.0015x over previous
//
#include <hip/hip_runtime.h>

#define F_TOTAL 128
#define N_HEADS 8
#define HEAD_DIM 16
#define SCAN_ITEMS 1024   // items per block in the node-histogram scan

typedef float vf4 __attribute__((ext_vector_type(4)));
typedef int   vi4 __attribute__((ext_vector_type(4)));
typedef float vf2 __attribute__((ext_vector_type(2)));

// ---------------------------------------------------------------------------
// Kernel 1: per-head linear projections q,k,v = x_h @ W_h^T  (fp32 in/out).
// Shuffle-based: no LDS, no barriers. Each thread owns one output feature f
// (f = tid&127 stays constant across grid-stride because stride % 128 == 0)
// and keeps the 3x16 weight rows in registers. k,v are stored INTERLEAVED
// as float2 {k,v} so the hot kernel gathers them with contiguous dwordx4.
// The pair histogram (independent work) is fused in to save a dispatch.
// ---------------------------------------------------------------------------
__global__ __launch_bounds__(256) void proj_hist_kernel(
    const float* __restrict__ x,
    const float* __restrict__ wq,
    const float* __restrict__ wk,
    const float* __restrict__ wv,
    const int*   __restrict__ idx_i,
    float* __restrict__ q, float* __restrict__ kv,
    int*   __restrict__ hist,
    int n_nodes, int n_pairs)
{
    const int gid = blockIdx.x * 256 + threadIdx.x;
    const int stride = gridDim.x * 256;
    const int f = gid & (F_TOTAL - 1);

    float rq[16], rk[16], rv[16];
    const float4* wq4 = (const float4*)wq;
    const float4* wk4 = (const float4*)wk;
    const float4* wv4 = (const float4*)wv;
    #pragma unroll
    for (int d4 = 0; d4 < 4; ++d4) {
        float4 a = wq4[f * 4 + d4];
        rq[d4*4+0]=a.x; rq[d4*4+1]=a.y; rq[d4*4+2]=a.z; rq[d4*4+3]=a.w;
        float4 b = wk4[f * 4 + d4];
        rk[d4*4+0]=b.x; rk[d4*4+1]=b.y; rk[d4*4+2]=b.z; rk[d4*4+3]=b.w;
        float4 c = wv4[f * 4 + d4];
        rv[d4*4+0]=c.x; rv[d4*4+1]=c.y; rv[d4*4+2]=c.z; rv[d4*4+3]=c.w;
    }
    // lane holding x[n][h*16+d] within this thread's wave
    const int lanebase = (f & 112) & 63;

    const int total = n_nodes * F_TOTAL;
    for (int idx = gid; idx < total; idx += stride) {
        const float xval = __builtin_nontemporal_load(x + idx);  // read-once
        float aq = 0.f, ak = 0.f, av = 0.f;
        #pragma unroll
        for (int d = 0; d < 16; ++d) {
            const float xv = __shfl(xval, lanebase + d);
            aq += xv * rq[d];
            ak += xv * rk[d];
            av += xv * rv[d];
        }
        q[idx] = aq;
        ((vf2*)kv)[idx] = (vf2){ak, av};
    }

    // fused pair histogram (grid covers 786k threads > 640k pairs)
    for (int p = gid; p < n_pairs; p += stride)
        atomicAdd(&hist[idx_i[p]], 1);
}

// ---------------------------------------------------------------------------
// Counting sort of pairs by idx_i: hist -> scan -> scatter. Payload packed
// into one int4 {p, j, phi_bits, 0}: one scattered 16B store per pair, one
// broadcast 16B load per pair in the hot kernel.
// ---------------------------------------------------------------------------
__global__ __launch_bounds__(256) void scan_reduce_kernel(
    const int* __restrict__ hist, int* __restrict__ blockSums, int n)
{
    __shared__ int ls[256];
    const int t = threadIdx.x;
    const int base = blockIdx.x * SCAN_ITEMS + t * 4;
    int s = 0;
    if (base + 3 < n) {
        int4 h = *(const int4*)(hist + base);
        s = h.x + h.y + h.z + h.w;
    } else {
        for (int kk = 0; kk < 4; ++kk)
            if (base + kk < n) s += hist[base + kk];
    }
    ls[t] = s;
    __syncthreads();
    for (int off = 128; off > 0; off >>= 1) {
        if (t < off) ls[t] += ls[t + off];
        __syncthreads();
    }
    if (t == 0) blockSums[blockIdx.x] = ls[0];
}

__global__ __launch_bounds__(128) void scan_spine_kernel(
    int* __restrict__ blockSums, int nblk)
{
    __shared__ int ls[128];
    const int t = threadIdx.x;
    const int val = (t < nblk) ? blockSums[t] : 0;
    ls[t] = val;
    __syncthreads();
    for (int off = 1; off < 128; off <<= 1) {
        int add = (t >= off) ? ls[t - off] : 0;
        __syncthreads();
        ls[t] += add;
        __syncthreads();
    }
    if (t < nblk) blockSums[t] = ls[t] - val;   // exclusive
}

__global__ __launch_bounds__(256) void scan_apply_kernel(
    const int* __restrict__ hist, const int* __restrict__ blockSums,
    int* __restrict__ offsets, int n)
{
    __shared__ int ls[256];
    const int t = threadIdx.x;
    const int base = blockIdx.x * SCAN_ITEMS + t * 4;
    int h0 = 0, h1 = 0, h2 = 0, h3 = 0;
    if (base + 3 < n) {
        int4 h = *(const int4*)(hist + base);
        h0 = h.x; h1 = h.y; h2 = h.z; h3 = h.w;
    } else {
        if (base + 0 < n) h0 = hist[base + 0];
        if (base + 1 < n) h1 = hist[base + 1];
        if (base + 2 < n) h2 = hist[base + 2];
        if (base + 3 < n) h3 = hist[base + 3];
    }
    const int tsum = h0 + h1 + h2 + h3;
    ls[t] = tsum;
    __syncthreads();
    for (int off = 1; off < 256; off <<= 1) {
        int add = (t >= off) ? ls[t - off] : 0;
        __syncthreads();
        ls[t] += add;
        __syncthreads();
    }
    int off = blockSums[blockIdx.x] + (ls[t] - tsum);   // exclusive base
    if (base + 0 < n) offsets[base + 0] = off; off += h0;
    if (base + 1 < n) offsets[base + 1] = off; off += h1;
    if (base + 2 < n) offsets[base + 2] = off; off += h2;
    if (base + 3 < n) offsets[base + 3] = off;
}

// scatter bumps offsets[] directly (no cursor array): afterwards
// offsets[i] == start_i + cnt_i, and the hot kernel recovers
// start_i = offsets[i] - hist[i].
__global__ __launch_bounds__(256) void scatter_kernel(
    const int* __restrict__ idx_i, const int* __restrict__ idx_j,
    const float* __restrict__ phi,
    int* __restrict__ offsets,
    vi4* __restrict__ meta,
    int n_pairs)
{
    const int p = blockIdx.x * 256 + threadIdx.x;
    if (p < n_pairs) {
        const int i = idx_i[p];
        const int pos = atomicAdd(&offsets[i], 1);
        meta[pos] = (vi4){p, idx_j[p], __float_as_int(phi[p]), 0};
    }
}

// ---------------------------------------------------------------------------
// Kernel 3: segmented attention aggregation — ONE NODE PER WAVE.
// Lanes 0-31 process even pairs, lanes 32-63 odd pairs of the SAME node,
// so iterations = ceil(cnt/2) exactly (no cross-node max divergence).
// Thread t = lane&31 owns features f = 4t..4t+3 (within one head: 4|16, so
// the 16-wide head reduce is shfl_xor 1,2 inside a half-wave). Depth-2 meta
// prefetch + 2-pair unroll per half keeps 4 independent gather chains in
// flight; meta has an 8-entry padded tail so prefetches need no bounds
// checks. Final shfl_xor(.,32) merges the two halves. w_ij is read
// nontemporally (stream-once) so the L3-resident kv set isn't evicted.
// ---------------------------------------------------------------------------
__global__ __launch_bounds__(256) void segment_kernel(
    const float* __restrict__ q,
    const float* __restrict__ kv,
    const float* __restrict__ w_ij,
    const int* __restrict__ hist,
    const int* __restrict__ offsets,
    const vi4* __restrict__ meta,
    float* __restrict__ out,
    int n_nodes)
{
    const int node = blockIdx.x * 4 + (threadIdx.x >> 6);
    if (node >= n_nodes) return;
    const int lane = threadIdx.x & 63;
    const int half = lane >> 5;          // 0: even pair slots, 1: odd
    const int t    = lane & 31;          // feature group f = 4t..4t+3

    const int cnt   = hist[node];
    const int start = offsets[node] - cnt;   // offsets were advanced by scatter
    const vf4 q4 = *((const vf4*)(q + (size_t)node * F_TOTAL) + t);

    vf4 acc = (vf4){0.f, 0.f, 0.f, 0.f};

    const int my0 = start + half;                       // my first pair slot
    const int rem = (cnt > half) ? ((cnt - half + 1) >> 1) : 0;  // my pair count

    if (rem > 0) {
        // depth-2 pipeline: m0/m1 are pairs my0+2r, my0+2r+2
        vi4 m0 = meta[my0];
        vi4 m1 = meta[my0 + 2];          // padded tail: always safe to load
        int r = 0;
        for (; r + 2 <= rem; r += 2) {
            const vi4 n0 = meta[my0 + 2 * (r + 2)];
            const vi4 n1 = meta[my0 + 2 * (r + 3)];
            const vf4 wA = __builtin_nontemporal_load(
                (const vf4*)(w_ij + (size_t)m0.x * F_TOTAL) + t);
            const vf4* kpA = (const vf4*)(kv + (size_t)m0.y * F_TOTAL * 2) + t * 2;
            const vf4 aA = kpA[0], bA = kpA[1];   // {k,v} interleaved
            const vf4 wB = __builtin_nontemporal_load(
                (const vf4*)(w_ij + (size_t)m1.x * F_TOTAL) + t);
            const vf4* kpB = (const vf4*)(kv + (size_t)m1.y * F_TOTAL * 2) + t * 2;
            const vf4 aB = kpB[0], bB = kpB[1];

            float sA = q4.x*wA.x*aA.x + q4.y*wA.y*aA.z + q4.z*wA.z*bA.x + q4.w*wA.w*bA.z;
            float sB = q4.x*wB.x*aB.x + q4.y*wB.y*aB.z + q4.z*wB.z*bB.x + q4.w*wB.w*bB.z;
            sA += __shfl_xor(sA, 1); sA += __shfl_xor(sA, 2);   // 16-wide head sum
            sB += __shfl_xor(sB, 1); sB += __shfl_xor(sB, 2);
            const float alA = sA * 0.25f * __int_as_float(m0.z);
            const float alB = sB * 0.25f * __int_as_float(m1.z);
            acc.x += alA * aA.y; acc.y += alA * aA.w;
            acc.z += alA * bA.y; acc.w += alA * bA.w;
            acc.x += alB * aB.y; acc.y += alB * aB.w;
            acc.z += alB * bB.y; acc.w += alB * bB.w;
            m0 = n0; m1 = n1;
        }
        if (r < rem) {   // odd tail: one more pair from m0
            const vf4 wA = __builtin_nontemporal_load(
                (const vf4*)(w_ij + (size_t)m0.x * F_TOTAL) + t);
            const vf4* kpA = (const vf4*)(kv + (size_t)m0.y * F_TOTAL * 2) + t * 2;
            const vf4 aA = kpA[0], bA = kpA[1];
            float sA = q4.x*wA.x*aA.x + q4.y*wA.y*aA.z + q4.z*wA.z*bA.x + q4.w*wA.w*bA.z;
            sA += __shfl_xor(sA, 1); sA += __shfl_xor(sA, 2);
            const float alA = sA * 0.25f * __int_as_float(m0.z);
            acc.x += alA * aA.y; acc.y += alA * aA.w;
            acc.z += alA * bA.y; acc.w += alA * bA.w;
        }
    }

    // merge the even-pair half with the odd-pair half
    acc.x += __shfl_xor(acc.x, 32);
    acc.y += __shfl_xor(acc.y, 32);
    acc.z += __shfl_xor(acc.z, 32);
    acc.w += __shfl_xor(acc.w, 32);
    if (half == 0)
        __builtin_nontemporal_store(acc, (vf4*)(out + (size_t)node * F_TOTAL) + t);
}

extern "C" void kernel_launch(void* const* d_in, const int* in_sizes, int n_in,
                              void* d_out, int out_size, void* d_ws, size_t ws_size,
                              hipStream_t stream)
{
    const float* x     = (const float*)d_in[0];
    const float* w_ij  = (const float*)d_in[1];
    const int*   idx_i = (const int*)d_in[2];
    const int*   idx_j = (const int*)d_in[3];
    const float* phi   = (const float*)d_in[4];
    const float* wq    = (const float*)d_in[5];
    const float* wk    = (const float*)d_in[6];
    const float* wv    = (const float*)d_in[7];

    const int n_nodes = in_sizes[0] / F_TOTAL;
    const int n_pairs = in_sizes[2];
    const size_t node_elems = (size_t)n_nodes * F_TOTAL;

    // workspace layout (16B-aligned segments first)
    float* q         = (float*)d_ws;                   // node_elems
    float* kv        = q + node_elems;                 // 2*node_elems (interleaved k,v)
    vi4*   meta      = (vi4*)(kv + 2 * node_elems);    // n_pairs + 8 (padded tail)
    int*   hist      = (int*)(meta + n_pairs + 8);     // n_nodes
    int*   offsets   = hist + n_nodes;                 // n_nodes
    int*   blockSums = offsets + n_nodes;              // <=128 (pad to 128)

    hipMemsetAsync(hist, 0, (size_t)n_nodes * sizeof(int), stream);

    proj_hist_kernel<<<3072, 256, 0, stream>>>(
        x, wq, wk, wv, idx_i, q, kv, hist, n_nodes, n_pairs);

    const int nblk = (n_nodes + SCAN_ITEMS - 1) / SCAN_ITEMS;   // 98 for 100k
    scan_reduce_kernel<<<nblk, 256, 0, stream>>>(hist, blockSums, n_nodes);
    scan_spine_kernel<<<1, 128, 0, stream>>>(blockSums, nblk);
    scan_apply_kernel<<<nblk, 256, 0, stream>>>(hist, blockSums, offsets, n_nodes);

    const int pair_blocks = (n_pairs + 255) / 256;
    scatter_kernel<<<pair_blocks, 256, 0, stream>>>(
        idx_i, idx_j, phi, offsets, meta, n_pairs);

    segment_kernel<<<(n_nodes + 3) / 4, 256, 0, stream>>>(
        q, kv, w_ij, hist, offsets, meta, (float*)d_out, n_nodes);
}

// Round 4
// 590.834 us; speedup vs baseline: 1.1742x; 1.0687x over previous
//
#include <hip/hip_runtime.h>
#include <hip/hip_fp16.h>

#define F_TOTAL 128
#define N_HEADS 8
#define HEAD_DIM 16
#define SCAN_ITEMS 1024   // items per block in the node-histogram scan

typedef float vf4 __attribute__((ext_vector_type(4)));
typedef int   vi4 __attribute__((ext_vector_type(4)));

// ---------------------------------------------------------------------------
// Kernel 1: per-head linear projections q,k,v = x_h @ W_h^T.
// q stays fp32; k,v are stored as INTERLEAVED fp16 half2 {k_f, v_f} per
// feature -> per node 128 half2 = 512B. The hot kernel then reads one
// dwordx4 (4 features' k AND v) per lane per pair: halves the random-gather
// traffic (655->327 MB) and the gathered working set (102->51 MB).
// fp16 rel err 2^-11 keeps absmax ~0.01-0.02 vs threshold 0.129.
// Pair histogram fused in (independent work, saves a dispatch).
// ---------------------------------------------------------------------------
__global__ __launch_bounds__(256) void proj_hist_kernel(
    const float* __restrict__ x,
    const float* __restrict__ wq,
    const float* __restrict__ wk,
    const float* __restrict__ wv,
    const int*   __restrict__ idx_i,
    float* __restrict__ q, __half2* __restrict__ kv,
    int*   __restrict__ hist,
    int n_nodes, int n_pairs)
{
    const int gid = blockIdx.x * 256 + threadIdx.x;
    const int stride = gridDim.x * 256;
    const int f = gid & (F_TOTAL - 1);

    float rq[16], rk[16], rv[16];
    const float4* wq4 = (const float4*)wq;
    const float4* wk4 = (const float4*)wk;
    const float4* wv4 = (const float4*)wv;
    #pragma unroll
    for (int d4 = 0; d4 < 4; ++d4) {
        float4 a = wq4[f * 4 + d4];
        rq[d4*4+0]=a.x; rq[d4*4+1]=a.y; rq[d4*4+2]=a.z; rq[d4*4+3]=a.w;
        float4 b = wk4[f * 4 + d4];
        rk[d4*4+0]=b.x; rk[d4*4+1]=b.y; rk[d4*4+2]=b.z; rk[d4*4+3]=b.w;
        float4 c = wv4[f * 4 + d4];
        rv[d4*4+0]=c.x; rv[d4*4+1]=c.y; rv[d4*4+2]=c.z; rv[d4*4+3]=c.w;
    }
    // lane holding x[n][h*16+d] within this thread's wave
    const int lanebase = (f & 112) & 63;

    const int total = n_nodes * F_TOTAL;
    for (int idx = gid; idx < total; idx += stride) {
        const float xval = __builtin_nontemporal_load(x + idx);  // read-once
        float aq = 0.f, ak = 0.f, av = 0.f;
        #pragma unroll
        for (int d = 0; d < 16; ++d) {
            const float xv = __shfl(xval, lanebase + d);
            aq += xv * rq[d];
            ak += xv * rk[d];
            av += xv * rv[d];
        }
        q[idx] = aq;
        kv[idx] = __floats2half2_rn(ak, av);   // {k, v} for feature f
    }

    // fused pair histogram (grid covers 786k threads > 640k pairs)
    for (int p = gid; p < n_pairs; p += stride)
        atomicAdd(&hist[idx_i[p]], 1);
}

// ---------------------------------------------------------------------------
// Counting sort of pairs by idx_i: hist -> scan (2 dispatches) -> scatter.
// Payload packed into one int4 {p, j, phi_bits, 0}.
// ---------------------------------------------------------------------------
__global__ __launch_bounds__(256) void scan_reduce_kernel(
    const int* __restrict__ hist, int* __restrict__ blockSums, int n)
{
    __shared__ int ls[256];
    const int t = threadIdx.x;
    const int base = blockIdx.x * SCAN_ITEMS + t * 4;
    int s = 0;
    if (base + 3 < n) {
        int4 h = *(const int4*)(hist + base);
        s = h.x + h.y + h.z + h.w;
    } else {
        for (int kk = 0; kk < 4; ++kk)
            if (base + kk < n) s += hist[base + kk];
    }
    ls[t] = s;
    __syncthreads();
    for (int off = 128; off > 0; off >>= 1) {
        if (t < off) ls[t] += ls[t + off];
        __syncthreads();
    }
    if (t == 0) blockSums[blockIdx.x] = ls[0];
}

// Spine fused in: each block redundantly sums blockSums[0..bid) itself
// (nblk = 98 values -> one masked load + block reduce), removing the
// single-block spine dispatch.
__global__ __launch_bounds__(256) void scan_apply_kernel(
    const int* __restrict__ hist, const int* __restrict__ blockSums,
    int* __restrict__ offsets, int n, int nblk)
{
    __shared__ int ls[256];
    const int t = threadIdx.x;
    const int bid = blockIdx.x;

    // base = sum of blockSums[0..bid)
    int s = 0;
    for (int b = t; b < bid; b += 256) s += blockSums[b];
    ls[t] = s;
    __syncthreads();
    for (int off = 128; off > 0; off >>= 1) {
        if (t < off) ls[t] += ls[t + off];
        __syncthreads();
    }
    const int base0 = ls[0];
    __syncthreads();   // ls reused below

    const int base = bid * SCAN_ITEMS + t * 4;
    int h0 = 0, h1 = 0, h2 = 0, h3 = 0;
    if (base + 3 < n) {
        int4 h = *(const int4*)(hist + base);
        h0 = h.x; h1 = h.y; h2 = h.z; h3 = h.w;
    } else {
        if (base + 0 < n) h0 = hist[base + 0];
        if (base + 1 < n) h1 = hist[base + 1];
        if (base + 2 < n) h2 = hist[base + 2];
        if (base + 3 < n) h3 = hist[base + 3];
    }
    const int tsum = h0 + h1 + h2 + h3;
    ls[t] = tsum;
    __syncthreads();
    for (int off = 1; off < 256; off <<= 1) {
        int add = (t >= off) ? ls[t - off] : 0;
        __syncthreads();
        ls[t] += add;
        __syncthreads();
    }
    int off = base0 + (ls[t] - tsum);   // exclusive base
    if (base + 0 < n) offsets[base + 0] = off; off += h0;
    if (base + 1 < n) offsets[base + 1] = off; off += h1;
    if (base + 2 < n) offsets[base + 2] = off; off += h2;
    if (base + 3 < n) offsets[base + 3] = off;
}

// scatter bumps offsets[] directly (no cursor array): afterwards
// offsets[i] == start_i + cnt_i, and the hot kernel recovers
// start_i = offsets[i] - hist[i].
__global__ __launch_bounds__(256) void scatter_kernel(
    const int* __restrict__ idx_i, const int* __restrict__ idx_j,
    const float* __restrict__ phi,
    int* __restrict__ offsets,
    vi4* __restrict__ meta,
    int n_pairs)
{
    const int p = blockIdx.x * 256 + threadIdx.x;
    if (p < n_pairs) {
        const int i = idx_i[p];
        const int pos = atomicAdd(&offsets[i], 1);
        meta[pos] = (vi4){p, idx_j[p], __float_as_int(phi[p]), 0};
    }
}

// ---------------------------------------------------------------------------
// Kernel 3: segmented attention aggregation — one node per wave.
// Lanes 0-31 even pair slots, 32-63 odd slots of the same node; thread
// t=lane&31 owns features 4t..4t+3 (within one head). Per pair per lane:
// one dwordx4 w load (nontemporal stream), ONE dwordx4 fp16 {k,v} load
// (halved gather bytes), head reduce = shfl_xor 1,2; final shfl_xor(.,32)
// merges halves. Depth-2 meta prefetch; meta has an 8-entry padded tail.
// ---------------------------------------------------------------------------
__global__ __launch_bounds__(256) void segment_kernel(
    const float* __restrict__ q,
    const __half2* __restrict__ kv,
    const float* __restrict__ w_ij,
    const int* __restrict__ hist,
    const int* __restrict__ offsets,
    const vi4* __restrict__ meta,
    float* __restrict__ out,
    int n_nodes)
{
    const int node = blockIdx.x * 4 + (threadIdx.x >> 6);
    if (node >= n_nodes) return;
    const int lane = threadIdx.x & 63;
    const int half = lane >> 5;
    const int t    = lane & 31;

    const int cnt   = hist[node];
    const int start = offsets[node] - cnt;   // offsets were advanced by scatter
    const vf4 q4 = *((const vf4*)(q + (size_t)node * F_TOTAL) + t);

    vf4 acc = (vf4){0.f, 0.f, 0.f, 0.f};

    const int my0 = start + half;
    const int rem = (cnt > half) ? ((cnt - half + 1) >> 1) : 0;

    union HU { vi4 i; __half2 h[4]; };

    if (rem > 0) {
        vi4 m0 = meta[my0];
        vi4 m1 = meta[my0 + 2];          // padded tail: always safe
        int r = 0;
        for (; r + 2 <= rem; r += 2) {
            const vi4 n0 = meta[my0 + 2 * (r + 2)];
            const vi4 n1 = meta[my0 + 2 * (r + 3)];
            const vf4 wA = __builtin_nontemporal_load(
                (const vf4*)(w_ij + (size_t)m0.x * F_TOTAL) + t);
            HU A; A.i = *((const vi4*)kv + (size_t)m0.y * 32 + t);
            const vf4 wB = __builtin_nontemporal_load(
                (const vf4*)(w_ij + (size_t)m1.x * F_TOTAL) + t);
            HU B; B.i = *((const vi4*)kv + (size_t)m1.y * 32 + t);

            const float2 a0 = __half22float2(A.h[0]);
            const float2 a1 = __half22float2(A.h[1]);
            const float2 a2 = __half22float2(A.h[2]);
            const float2 a3 = __half22float2(A.h[3]);
            const float2 b0 = __half22float2(B.h[0]);
            const float2 b1 = __half22float2(B.h[1]);
            const float2 b2 = __half22float2(B.h[2]);
            const float2 b3 = __half22float2(B.h[3]);

            float sA = q4.x*wA.x*a0.x + q4.y*wA.y*a1.x + q4.z*wA.z*a2.x + q4.w*wA.w*a3.x;
            float sB = q4.x*wB.x*b0.x + q4.y*wB.y*b1.x + q4.z*wB.z*b2.x + q4.w*wB.w*b3.x;
            sA += __shfl_xor(sA, 1); sA += __shfl_xor(sA, 2);   // 16-wide head sum
            sB += __shfl_xor(sB, 1); sB += __shfl_xor(sB, 2);
            const float alA = sA * 0.25f * __int_as_float(m0.z);
            const float alB = sB * 0.25f * __int_as_float(m1.z);
            acc.x += alA * a0.y; acc.y += alA * a1.y;
            acc.z += alA * a2.y; acc.w += alA * a3.y;
            acc.x += alB * b0.y; acc.y += alB * b1.y;
            acc.z += alB * b2.y; acc.w += alB * b3.y;
            m0 = n0; m1 = n1;
        }
        if (r < rem) {   // odd tail: one more pair from m0
            const vf4 wA = __builtin_nontemporal_load(
                (const vf4*)(w_ij + (size_t)m0.x * F_TOTAL) + t);
            HU A; A.i = *((const vi4*)kv + (size_t)m0.y * 32 + t);
            const float2 a0 = __half22float2(A.h[0]);
            const float2 a1 = __half22float2(A.h[1]);
            const float2 a2 = __half22float2(A.h[2]);
            const float2 a3 = __half22float2(A.h[3]);
            float sA = q4.x*wA.x*a0.x + q4.y*wA.y*a1.x + q4.z*wA.z*a2.x + q4.w*wA.w*a3.x;
            sA += __shfl_xor(sA, 1); sA += __shfl_xor(sA, 2);
            const float alA = sA * 0.25f * __int_as_float(m0.z);
            acc.x += alA * a0.y; acc.y += alA * a1.y;
            acc.z += alA * a2.y; acc.w += alA * a3.y;
        }
    }

    // merge the even-pair half with the odd-pair half
    acc.x += __shfl_xor(acc.x, 32);
    acc.y += __shfl_xor(acc.y, 32);
    acc.z += __shfl_xor(acc.z, 32);
    acc.w += __shfl_xor(acc.w, 32);
    if (half == 0)
        __builtin_nontemporal_store(acc, (vf4*)(out + (size_t)node * F_TOTAL) + t);
}

extern "C" void kernel_launch(void* const* d_in, const int* in_sizes, int n_in,
                              void* d_out, int out_size, void* d_ws, size_t ws_size,
                              hipStream_t stream)
{
    const float* x     = (const float*)d_in[0];
    const float* w_ij  = (const float*)d_in[1];
    const int*   idx_i = (const int*)d_in[2];
    const int*   idx_j = (const int*)d_in[3];
    const float* phi   = (const float*)d_in[4];
    const float* wq    = (const float*)d_in[5];
    const float* wk    = (const float*)d_in[6];
    const float* wv    = (const float*)d_in[7];

    const int n_nodes = in_sizes[0] / F_TOTAL;
    const int n_pairs = in_sizes[2];
    const size_t node_elems = (size_t)n_nodes * F_TOTAL;

    // workspace layout (16B-aligned segments first)
    float*   q         = (float*)d_ws;                    // node_elems f32
    __half2* kv        = (__half2*)(q + node_elems);      // node_elems half2 (51MB)
    vi4*     meta      = (vi4*)((char*)kv + node_elems * sizeof(__half2)); // n_pairs+8
    int*     hist      = (int*)(meta + n_pairs + 8);      // n_nodes
    int*     offsets   = hist + n_nodes;                  // n_nodes
    int*     blockSums = offsets + n_nodes;               // <=128

    hipMemsetAsync(hist, 0, (size_t)n_nodes * sizeof(int), stream);

    proj_hist_kernel<<<3072, 256, 0, stream>>>(
        x, wq, wk, wv, idx_i, q, kv, hist, n_nodes, n_pairs);

    const int nblk = (n_nodes + SCAN_ITEMS - 1) / SCAN_ITEMS;   // 98 for 100k
    scan_reduce_kernel<<<nblk, 256, 0, stream>>>(hist, blockSums, n_nodes);
    scan_apply_kernel<<<nblk, 256, 0, stream>>>(hist, blockSums, offsets,
                                                n_nodes, nblk);

    const int pair_blocks = (n_pairs + 255) / 256;
    scatter_kernel<<<pair_blocks, 256, 0, stream>>>(
        idx_i, idx_j, phi, offsets, meta, n_pairs);

    segment_kernel<<<(n_nodes + 3) / 4, 256, 0, stream>>>(
        q, kv, w_ij, hist, offsets, meta, (float*)d_out, n_nodes);
}